// Round 11
// baseline (400.316 us; speedup 1.0000x reference)
//
#include <hip/hip_runtime.h>
#include <hip/hip_bf16.h>

#define KK 4096
#define NN 4096

using f32x16 = __attribute__((ext_vector_type(16))) float;
using bf16x8 = __attribute__((ext_vector_type(8))) short;

static __device__ __forceinline__ unsigned short f2bf(float f) {
    union { __hip_bfloat16 h; unsigned short u; } cv;
    cv.h = __float2bfloat16(f);
    return cv.u;
}

// ---- prep: x (fp32) -> bf16 bits --------------------------------------------
__global__ __launch_bounds__(256) void prep_x_kernel(const float4* __restrict__ in,
                                                     ushort4* __restrict__ out, int n4) {
    for (int i = blockIdx.x * blockDim.x + threadIdx.x; i < n4; i += gridDim.x * blockDim.x) {
        float4 a = in[i];
        ushort4 o;
        o.x = f2bf(a.x); o.y = f2bf(a.y); o.z = f2bf(a.z); o.w = f2bf(a.w);
        out[i] = o;
    }
}

// ---- prep: W = sw + bb (sw is pre-masked: sw*sm == sw exactly) --------------
__global__ __launch_bounds__(256) void prep_w_kernel(const float4* __restrict__ sw,
                                                     const float4* __restrict__ bb,
                                                     ushort4* __restrict__ out, int n4) {
    for (int i = blockIdx.x * blockDim.x + threadIdx.x; i < n4; i += gridDim.x * blockDim.x) {
        float4 a = sw[i], b = bb[i];
        ushort4 o;
        o.x = f2bf(a.x + b.x);
        o.y = f2bf(a.y + b.y);
        o.z = f2bf(a.z + b.z);
        o.w = f2bf(a.w + b.w);
        out[i] = o;
    }
}

// ---- main GEMM: C[M,N] = A[M,K] * B[N,K]^T + bias ---------------------------
// R11 dual-block-overlap: 4 waves/block (2Mx2N of 128x64), tile 256x128, BK=32,
// 3-buffer LDS ring (72KB -> 2 independent blocks/CU; their phase offset lets
// one block's ds_reads overlap the other's MFMA burst -- m114 mechanism).
// 32x32x16 MFMA; slot(0..3) ^= (row>>1)&3 swizzle (4-way floor for 64B rows)
// via pre-swizzled global source; stage-ahead-2 into buf (t+2)%3; vmcnt(6)/round.
__global__ __launch_bounds__(256, 2) void gemm_db(const short* __restrict__ A,  // [M][K] bf16
                                                  const short* __restrict__ B,  // [N][K] bf16
                                                  const float* __restrict__ bias,
                                                  float* __restrict__ C, int M) {
    __shared__ __align__(16) short As[3][8192];  // 3 x (256 rows x 32 k) = 48KB
    __shared__ __align__(16) short Bs[3][4096];  // 3 x (128 rows x 32 k) = 24KB

    const int tid  = threadIdx.x;
    const int lane = tid & 63;
    const int w    = tid >> 6;         // 0..3
    const int wr   = w >> 1;           // 0..1 -> 128-row band
    const int wc   = w & 1;            // 0..1 -> 64-col band
    const int l31  = lane & 31;
    const int l5   = lane >> 5;        // 0..1
    const int sl3  = (l31 >> 1) & 3;   // read-side swizzle key

    // XCD-bijective swizzle (nwg = 1024, divisible by 8)
    const int bid = blockIdx.x;
    const int swz = (bid & 7) * 128 + (bid >> 3);
    const int bm  = (swz >> 5) * 256;   // 32 M-tiles
    const int bn  = (swz & 31) * 128;   // 32 N-tiles

    // stage addressing: one instr = 16 rows x 64B; lane -> (row=lane>>2, slot=lane&3)
    // LDS[r][s] = G[r][s ^ ((r>>1)&3)]; within a 16-row chunk (r>>1)&3 == (lane>>3)&3
    const int srow_c = lane >> 2;                              // 0..15
    const int scol   = ((lane & 3) ^ ((lane >> 3) & 3)) * 8;   // shorts
    const short* Abase = A + (size_t)(bm + srow_c) * KK + scol;
    const short* Bbase = B + (size_t)(bn + srow_c) * KK + scol;

    auto stageA = [&](int buf, int t, int j) {   // chunk = w*4+j (16 rows)
        const int cA = w * 4 + j;
        __builtin_amdgcn_global_load_lds(
            (const __attribute__((address_space(1))) void*)(Abase + (size_t)cA * 16 * KK + t * 32),
            (__attribute__((address_space(3))) void*)(&As[buf][cA * 512]), 16, 0, 0);
    };
    auto stageB = [&](int buf, int t, int j) {   // chunk = w*2+j
        const int cB = w * 2 + j;
        __builtin_amdgcn_global_load_lds(
            (const __attribute__((address_space(1))) void*)(Bbase + (size_t)cB * 16 * KK + t * 32),
            (__attribute__((address_space(3))) void*)(&Bs[buf][cB * 512]), 16, 0, 0);
    };

    // fragment reads: row*32 shorts/row; slot = (ks*2+l5) ^ sl3
    auto rdA = [&](bf16x8 (&dst)[2][2], int buf, int fmB) {
#pragma unroll
        for (int fm = 0; fm < 2; ++fm)
#pragma unroll
            for (int ks = 0; ks < 2; ++ks) {
                const int row  = wr * 128 + (fmB + fm) * 32 + l31;
                const int slot = (ks * 2 + l5) ^ sl3;
                dst[fm][ks] = *(const bf16x8*)&As[buf][row * 32 + slot * 8];
            }
    };
    auto rdB = [&](bf16x8 (&dst)[2][2], int buf) {
#pragma unroll
        for (int fn = 0; fn < 2; ++fn)
#pragma unroll
            for (int ks = 0; ks < 2; ++ks) {
                const int row  = wc * 64 + fn * 32 + l31;
                const int slot = (ks * 2 + l5) ^ sl3;
                dst[fn][ks] = *(const bf16x8*)&Bs[buf][row * 32 + slot * 8];
            }
    };

    f32x16 acc[4][2] = {};              // 128 VGPR-equivalents
    bf16x8 AF1[2][2], AF2[2][2], BF[2][2];

    auto mm8 = [&](const bf16x8 (&af)[2][2], const bf16x8 (&bf)[2][2], int fmOff) {
#pragma unroll
        for (int ks = 0; ks < 2; ++ks)
#pragma unroll
            for (int fm = 0; fm < 2; ++fm)
#pragma unroll
                for (int fn = 0; fn < 2; ++fn)
                    acc[fmOff + fm][fn] = __builtin_amdgcn_mfma_f32_32x32x16_bf16(
                        af[fm][ks], bf[fn][ks], acc[fmOff + fm][fn], 0, 0, 0);
    };

    // prologue: stage t0 -> buf0 (6 instr), t1 -> buf1 (6); wait t0; barrier
#pragma unroll
    for (int j = 0; j < 4; ++j) stageA(0, 0, j);
#pragma unroll
    for (int j = 0; j < 2; ++j) stageB(0, 0, j);
#pragma unroll
    for (int j = 0; j < 4; ++j) stageA(1, 1, j);
#pragma unroll
    for (int j = 0; j < 2; ++j) stageB(1, 1, j);
    asm volatile("s_waitcnt vmcnt(6)" ::: "memory");
    __builtin_amdgcn_s_barrier();
    asm volatile("" ::: "memory");

    const int NT = KK / 32;   // 128 rounds
    int cur = 0;              // t % 3
    for (int t = 0; t < NT; ++t) {
        const int st   = (cur + 2 >= 3) ? cur - 1 : cur + 2;   // (t+2)%3
        const bool more = (t + 2 < NT);

        // ---- P1: read A fm01 + B (buf cur); stage 3 of tile t+2 ----
        rdA(AF1, cur, 0);
        rdB(BF, cur);
        if (more) { stageA(st, t + 2, 0); stageA(st, t + 2, 1); stageA(st, t + 2, 2); }
        __builtin_amdgcn_s_barrier();
        __builtin_amdgcn_s_setprio(1);
        mm8(AF1, BF, 0);
        __builtin_amdgcn_s_setprio(0);
        __builtin_amdgcn_s_barrier();
        asm volatile("" ::: "memory");

        // ---- P2: read A fm23; stage 3; counted vmcnt; MFMA ----
        rdA(AF2, cur, 2);
        if (more) { stageA(st, t + 2, 3); stageB(st, t + 2, 0); stageB(st, t + 2, 1); }
        if (more) { asm volatile("s_waitcnt vmcnt(6)" ::: "memory"); }
        else      { asm volatile("s_waitcnt vmcnt(0)" ::: "memory"); }
        __builtin_amdgcn_s_barrier();
        __builtin_amdgcn_s_setprio(1);
        mm8(AF2, BF, 2);
        __builtin_amdgcn_s_setprio(0);
        __builtin_amdgcn_s_barrier();
        asm volatile("" ::: "memory");

        cur = (cur + 1 >= 3) ? 0 : cur + 1;
    }

    // epilogue: 32x32 C/D layout col=lane&31, row=(reg&3)+8*(reg>>2)+4*(lane>>5)
#pragma unroll
    for (int fn = 0; fn < 2; ++fn) {
        const int col = bn + wc * 64 + fn * 32 + l31;
        const float bv = bias[col];
#pragma unroll
        for (int fm = 0; fm < 4; ++fm) {
#pragma unroll
            for (int r = 0; r < 16; ++r) {
                const int row = bm + wr * 128 + fm * 32 + (r & 3) + 8 * (r >> 2) + 4 * l5;
                C[(size_t)row * NN + col] = acc[fm][fn][r] + bv;
            }
        }
    }
}

// ---- fp32 fallback (only if workspace too small / odd shape) ----------------
__global__ __launch_bounds__(256) void fallback_gemm(const float* __restrict__ X,
                                                     const float* __restrict__ SW,
                                                     const float* __restrict__ SM,
                                                     const float* __restrict__ BB,
                                                     const float* __restrict__ bias,
                                                     float* __restrict__ C,
                                                     int M, int N, int K) {
    __shared__ float Xs[32][33];
    __shared__ float Ws[32][33];
    const int tid = threadIdx.x;
    const int tx = tid & 31;
    const int ty = tid >> 5;
    const int bm = blockIdx.x * 32, bn = blockIdx.y * 32;
    float acc[4] = {0.f, 0.f, 0.f, 0.f};
    for (int kt = 0; kt < K; kt += 32) {
#pragma unroll
        for (int r = 0; r < 4; ++r) {
            const int row = ty + r * 8;
            Xs[row][tx] = X[(size_t)(bm + row) * K + kt + tx];
            const size_t wi = (size_t)(bn + row) * K + kt + tx;
            Ws[row][tx] = SW[wi] * SM[wi] + BB[wi];
        }
        __syncthreads();
#pragma unroll 8
        for (int k = 0; k < 32; ++k) {
            const float wv = Ws[tx][k];
#pragma unroll
            for (int r = 0; r < 4; ++r)
                acc[r] += Xs[ty + r * 8][k] * wv;
        }
        __syncthreads();
    }
#pragma unroll
    for (int r = 0; r < 4; ++r)
        C[(size_t)(bm + ty + r * 8) * N + bn + tx] = acc[r] + bias[bn + tx];
}

extern "C" void kernel_launch(void* const* d_in, const int* in_sizes, int n_in,
                              void* d_out, int out_size, void* d_ws, size_t ws_size,
                              hipStream_t stream) {
    const float* x    = (const float*)d_in[0];
    const float* sw   = (const float*)d_in[1];
    const float* sm   = (const float*)d_in[2];
    const float* bb   = (const float*)d_in[3];
    const float* bias = (const float*)d_in[4];
    float* out = (float*)d_out;

    const int K = 4096;
    const int N = 4096;
    const int M = in_sizes[0] / K;   // 8192

    const size_t xb_bytes = (size_t)M * K * sizeof(short);
    const size_t wb_bytes = (size_t)N * K * sizeof(short);

    if (ws_size < xb_bytes + wb_bytes || (M % 256) != 0 || in_sizes[1] != N * K) {
        dim3 grid(M / 32, N / 32);
        fallback_gemm<<<grid, 256, 0, stream>>>(x, sw, sm, bb, bias, out, M, N, K);
        return;
    }

    short* xb = (short*)d_ws;
    short* wb = (short*)((char*)d_ws + xb_bytes);

    prep_x_kernel<<<2048, 256, 0, stream>>>((const float4*)x, (ushort4*)xb, (M * K) / 4);
    prep_w_kernel<<<2048, 256, 0, stream>>>((const float4*)sw, (const float4*)bb,
                                            (ushort4*)wb, (N * K) / 4);

    const int nwg = (M / 256) * (N / 128);   // 1024
    gemm_db<<<nwg, 256, 0, stream>>>(xb, wb, bias, out, M);
}

// Round 12
// 333.578 us; speedup vs baseline: 1.2001x; 1.2001x over previous
//
#include <hip/hip_runtime.h>
#include <hip/hip_bf16.h>

#define KK 4096
#define NN 4096

using f32x16 = __attribute__((ext_vector_type(16))) float;
using bf16x8 = __attribute__((ext_vector_type(8))) short;

static __device__ __forceinline__ unsigned short f2bf(float f) {
    union { __hip_bfloat16 h; unsigned short u; } cv;
    cv.h = __float2bfloat16(f);
    return cv.u;
}

// ---- prep: x (fp32) -> bf16 bits --------------------------------------------
__global__ __launch_bounds__(256) void prep_x_kernel(const float4* __restrict__ in,
                                                     ushort4* __restrict__ out, int n4) {
    for (int i = blockIdx.x * blockDim.x + threadIdx.x; i < n4; i += gridDim.x * blockDim.x) {
        float4 a = in[i];
        ushort4 o;
        o.x = f2bf(a.x); o.y = f2bf(a.y); o.z = f2bf(a.z); o.w = f2bf(a.w);
        out[i] = o;
    }
}

// ---- prep: W = sw + bb (sw is pre-masked: sw*sm == sw exactly) --------------
__global__ __launch_bounds__(256) void prep_w_kernel(const float4* __restrict__ sw,
                                                     const float4* __restrict__ bb,
                                                     ushort4* __restrict__ out, int n4) {
    for (int i = blockIdx.x * blockDim.x + threadIdx.x; i < n4; i += gridDim.x * blockDim.x) {
        float4 a = sw[i], b = bb[i];
        ushort4 o;
        o.x = f2bf(a.x + b.x);
        o.y = f2bf(a.y + b.y);
        o.z = f2bf(a.z + b.z);
        o.w = f2bf(a.w + b.w);
        out[i] = o;
    }
}

// ---- main GEMM: C[M,N] = A[M,K] * B[N,K]^T + bias ---------------------------
// R12 = R9 with MINIMAL BARRIERS. Hazard ledger: reads P1-P3 from As[0]/Bs[0];
// writes P1,P2->As[1], P3,P4->Bs[0], P5,P6->As[0], P7,P8->Bs[1]. Only 4 WAR
// windows per iter (P2->P3 Bs0, P4->P5 As0, P6->P7 Bs1, P8->P1' As1) => 4
// barriers/iter (was 16). Waves free-run inside 2-phase regions; skew staggers
// each wave's ds_read burst against others' MFMA bursts (m114 pipe overlap).
// lgkmcnt(0) before each region barrier closes the cross-wave in-flight
// ds_read vs ds_write order hazard. vmcnt ledger identical to R9.
__global__ __launch_bounds__(512, 2) void gemm_8p(const short* __restrict__ A,  // [M][K] bf16
                                                  const short* __restrict__ B,  // [N][K] bf16
                                                  const float* __restrict__ bias,
                                                  float* __restrict__ C, int M) {
    __shared__ __align__(16) short As[2][2][8192];  // [buf][half][128 rows x 64 k]
    __shared__ __align__(16) short Bs[2][2][8192];

    const int tid  = threadIdx.x;
    const int lane = tid & 63;
    const int w    = tid >> 6;         // 0..7
    const int wr   = w >> 2;           // 0..1 (A half)
    const int wc   = w & 3;            // 0..3
    const int bh   = wc >> 1;          // B half
    const int l31  = lane & 31;
    const int l5   = lane >> 5;        // 0..1
    const int l7   = lane & 7;

    // XCD-bijective swizzle (nwg = 512, divisible by 8)
    const int bid = blockIdx.x;
    const int swz = (bid & 7) * 64 + (bid >> 3);
    const int bm  = (swz >> 4) * 256;
    const int bn  = (swz & 15) * 256;

    // stage addressing: 8 rows x 128B per wave-instr; LDS[r][s] = G[r][s^(r&7)]
    const int srow = lane >> 3;
    const int scol = (l7 ^ srow) * 8;   // shorts
    const short* Abase = A + (size_t)bm * KK + scol;
    const short* Bbase = B + (size_t)bn * KK + scol;

#define STAGE_A(t, h)                                                                      \
    do {                                                                                   \
        _Pragma("unroll") for (int j = 0; j < 2; ++j) {                                    \
            const int rr = (h) * 128 + (w * 2 + j) * 8 + srow;                             \
            __builtin_amdgcn_global_load_lds(                                              \
                (const __attribute__((address_space(1))) void*)(Abase + (size_t)rr * KK + (t) * 64), \
                (__attribute__((address_space(3))) void*)(&As[(t) & 1][h][(w * 2 + j) * 512]), \
                16, 0, 0);                                                                 \
        }                                                                                  \
    } while (0)
#define STAGE_B(t, h)                                                                      \
    do {                                                                                   \
        _Pragma("unroll") for (int j = 0; j < 2; ++j) {                                    \
            const int rr = (h) * 128 + (w * 2 + j) * 8 + srow;                             \
            __builtin_amdgcn_global_load_lds(                                              \
                (const __attribute__((address_space(1))) void*)(Bbase + (size_t)rr * KK + (t) * 64), \
                (__attribute__((address_space(3))) void*)(&Bs[(t) & 1][h][(w * 2 + j) * 512]), \
                16, 0, 0);                                                                 \
        }                                                                                  \
    } while (0)

// region-end sync: own LDS queue drained (cross-wave ds order guard), barrier
#define REGION_BAR()                                          \
    asm volatile("s_waitcnt lgkmcnt(0)" ::: "memory");        \
    __builtin_amdgcn_s_barrier();                             \
    asm volatile("" ::: "memory")

    f32x16 acc[4][2] = {};              // [fm][fn] of 32x32 frags -> 128 VGPRs
    bf16x8 AF1[2][4], AF2[2][4], BF1[4], BF2[4];

    // fragment readers: row = base + fm*32 + l31; k-slot = (ks*2 + l5) ^ (row&7)
    auto rdA = [&](bf16x8 (&dst)[2][4], int buf, int fmBase) {
#pragma unroll
        for (int fm = 0; fm < 2; ++fm)
#pragma unroll
            for (int ks = 0; ks < 4; ++ks) {
                const int row  = (fmBase + fm) * 32 + l31;
                const int slot = (ks * 2 + l5) ^ l7;
                dst[fm][ks] = *(const bf16x8*)&As[buf][wr][row * 64 + slot * 8];
            }
    };
    auto rdB = [&](bf16x8 (&dst)[4], int buf, int rowBase) {
#pragma unroll
        for (int ks = 0; ks < 4; ++ks) {
            const int row  = rowBase + l31;
            const int slot = (ks * 2 + l5) ^ l7;
            dst[ks] = *(const bf16x8*)&Bs[buf][bh][row * 64 + slot * 8];
        }
    };
    auto mmq = [&](f32x16& a0, f32x16& a1, const bf16x8 (&af)[2][4], const bf16x8 (&bf)[4]) {
        __builtin_amdgcn_s_setprio(1);
#pragma unroll
        for (int ks = 0; ks < 4; ++ks) {
            a0 = __builtin_amdgcn_mfma_f32_32x32x16_bf16(af[0][ks], bf[ks], a0, 0, 0, 0);
            a1 = __builtin_amdgcn_mfma_f32_32x32x16_bf16(af[1][ks], bf[ks], a1, 0, 0, 0);
        }
        __builtin_amdgcn_s_setprio(0);
    };

    const int bRow0 = (wc & 1) * 64;    // B within-half row base for fn0

    // prologue: tile0 (A+B) and tile1 B; wait tile0 (leave B1's 4 in flight)
    STAGE_A(0, 0); STAGE_A(0, 1);
    STAGE_B(0, 0); STAGE_B(0, 1);
    STAGE_B(1, 0); STAGE_B(1, 1);
    asm volatile("s_waitcnt vmcnt(4)" ::: "memory");
    __builtin_amdgcn_s_barrier();
    asm volatile("" ::: "memory");

    const int NITER = KK / 128;   // 32 iterations, 2 K-tiles each
    for (int i = 0; i < NITER; ++i) {
        const int t = 2 * i;
        const bool more = (i < NITER - 1);

        // ======== region R1 = P1+P2 (free-run; last Bs[0] read here) ========
        // P1: read A fm0-1 + B fn0 (buf0); stage A(t+1)h0; MFMA
        rdA(AF1, 0, 0);
        rdB(BF1, 0, bRow0);
        STAGE_A(t + 1, 0);
        mmq(acc[0][0], acc[1][0], AF1, BF1);
        // P2: read B fn1; stage A(t+1)h1; MFMA
        rdB(BF2, 0, bRow0 + 32);
        STAGE_A(t + 1, 1);
        mmq(acc[0][1], acc[1][1], AF1, BF2);
        REGION_BAR();   // before P3's Bs[0] overwrite

        // ======== region R2 = P3+P4 (stages Bs[0]; last As[0] read here) ====
        // P3: read A fm2-3; stage B(t+2)h0; MFMA
        rdA(AF2, 0, 2);
        if (more) STAGE_B(t + 2, 0);
        mmq(acc[2][1], acc[3][1], AF2, BF2);
        // P4: stage B(t+2)h1; MFMA; counted vmcnt
        if (more) STAGE_B(t + 2, 1);
        mmq(acc[2][0], acc[3][0], AF2, BF1);
        asm volatile("s_waitcnt lgkmcnt(0)" ::: "memory");
        if (more) { asm volatile("s_waitcnt vmcnt(4)" ::: "memory"); }
        else      { asm volatile("s_waitcnt vmcnt(0)" ::: "memory"); }
        __builtin_amdgcn_s_barrier();
        asm volatile("" ::: "memory");

        // ======== region R3 = P5+P6 (stages As[0]; last Bs[1] read here) ====
        // P5: read tile t+1 (buf1) A fm0-1 + B fn0; stage A(t+2)h0; MFMA
        rdA(AF1, 1, 0);
        rdB(BF1, 1, bRow0);
        if (more) STAGE_A(t + 2, 0);
        mmq(acc[0][0], acc[1][0], AF1, BF1);
        // P6: read B fn1; stage A(t+2)h1; MFMA
        rdB(BF2, 1, bRow0 + 32);
        if (more) STAGE_A(t + 2, 1);
        mmq(acc[0][1], acc[1][1], AF1, BF2);
        REGION_BAR();   // before P7's Bs[1] overwrite

        // ======== region R4 = P7+P8 (stages Bs[1]; last As[1] read here) ====
        // P7: read A fm2-3; stage B(t+3)h0; MFMA
        rdA(AF2, 1, 2);
        if (more) STAGE_B(t + 3, 0);
        mmq(acc[2][1], acc[3][1], AF2, BF2);
        // P8: stage B(t+3)h1; MFMA; counted vmcnt
        if (more) STAGE_B(t + 3, 1);
        mmq(acc[2][0], acc[3][0], AF2, BF1);
        asm volatile("s_waitcnt lgkmcnt(0)" ::: "memory");
        if (more) { asm volatile("s_waitcnt vmcnt(4)" ::: "memory"); }
        else      { asm volatile("s_waitcnt vmcnt(0)" ::: "memory"); }
        __builtin_amdgcn_s_barrier();
        asm volatile("" ::: "memory");
    }

#undef STAGE_A
#undef STAGE_B
#undef REGION_BAR

    // epilogue: 32x32 C/D layout col=lane&31, row=(reg&3)+8*(reg>>2)+4*(lane>>5)
#pragma unroll
    for (int fn = 0; fn < 2; ++fn) {
        const int col = bn + wc * 64 + fn * 32 + l31;
        const float bv = bias[col];
#pragma unroll
        for (int fm = 0; fm < 4; ++fm) {
#pragma unroll
            for (int r = 0; r < 16; ++r) {
                const int row = bm + wr * 128 + fm * 32 + (r & 3) + 8 * (r >> 2) + 4 * l5;
                C[(size_t)row * NN + col] = acc[fm][fn][r] + bv;
            }
        }
    }
}

// ---- fp32 fallback (only if workspace too small / odd shape) ----------------
__global__ __launch_bounds__(256) void fallback_gemm(const float* __restrict__ X,
                                                     const float* __restrict__ SW,
                                                     const float* __restrict__ SM,
                                                     const float* __restrict__ BB,
                                                     const float* __restrict__ bias,
                                                     float* __restrict__ C,
                                                     int M, int N, int K) {
    __shared__ float Xs[32][33];
    __shared__ float Ws[32][33];
    const int tid = threadIdx.x;
    const int tx = tid & 31;
    const int ty = tid >> 5;
    const int bm = blockIdx.x * 32, bn = blockIdx.y * 32;
    float acc[4] = {0.f, 0.f, 0.f, 0.f};
    for (int kt = 0; kt < K; kt += 32) {
#pragma unroll
        for (int r = 0; r < 4; ++r) {
            const int row = ty + r * 8;
            Xs[row][tx] = X[(size_t)(bm + row) * K + kt + tx];
            const size_t wi = (size_t)(bn + row) * K + kt + tx;
            Ws[row][tx] = SW[wi] * SM[wi] + BB[wi];
        }
        __syncthreads();
#pragma unroll 8
        for (int k = 0; k < 32; ++k) {
            const float wv = Ws[tx][k];
#pragma unroll
            for (int r = 0; r < 4; ++r)
                acc[r] += Xs[ty + r * 8][k] * wv;
        }
        __syncthreads();
    }
#pragma unroll
    for (int r = 0; r < 4; ++r)
        C[(size_t)(bm + ty + r * 8) * N + bn + tx] = acc[r] + bias[bn + tx];
}

extern "C" void kernel_launch(void* const* d_in, const int* in_sizes, int n_in,
                              void* d_out, int out_size, void* d_ws, size_t ws_size,
                              hipStream_t stream) {
    const float* x    = (const float*)d_in[0];
    const float* sw   = (const float*)d_in[1];
    const float* sm   = (const float*)d_in[2];
    const float* bb   = (const float*)d_in[3];
    const float* bias = (const float*)d_in[4];
    float* out = (float*)d_out;

    const int K = 4096;
    const int N = 4096;
    const int M = in_sizes[0] / K;   // 8192

    const size_t xb_bytes = (size_t)M * K * sizeof(short);
    const size_t wb_bytes = (size_t)N * K * sizeof(short);

    if (ws_size < xb_bytes + wb_bytes || (M % 256) != 0 || in_sizes[1] != N * K) {
        dim3 grid(M / 32, N / 32);
        fallback_gemm<<<grid, 256, 0, stream>>>(x, sw, sm, bb, bias, out, M, N, K);
        return;
    }

    short* xb = (short*)d_ws;
    short* wb = (short*)((char*)d_ws + xb_bytes);

    prep_x_kernel<<<2048, 256, 0, stream>>>((const float4*)x, (ushort4*)xb, (M * K) / 4);
    prep_w_kernel<<<2048, 256, 0, stream>>>((const float4*)sw, (const float4*)bb,
                                            (ushort4*)wb, (N * K) / 4);

    const int nwg = (M / 256) * (N / 256);   // 512
    gemm_8p<<<nwg, 512, 0, stream>>>(xb, wb, bias, out, M);
}

// Round 13
// 326.232 us; speedup vs baseline: 1.2271x; 1.0225x over previous
//
#include <hip/hip_runtime.h>
#include <hip/hip_bf16.h>

#define KK 4096
#define NN 4096

using f32x16 = __attribute__((ext_vector_type(16))) float;
using bf16x8 = __attribute__((ext_vector_type(8))) short;

static __device__ __forceinline__ unsigned short f2bf(float f) {
    union { __hip_bfloat16 h; unsigned short u; } cv;
    cv.h = __float2bfloat16(f);
    return cv.u;
}

// ---- prep: x (fp32) -> bf16 bits --------------------------------------------
__global__ __launch_bounds__(256) void prep_x_kernel(const float4* __restrict__ in,
                                                     ushort4* __restrict__ out, int n4) {
    for (int i = blockIdx.x * blockDim.x + threadIdx.x; i < n4; i += gridDim.x * blockDim.x) {
        float4 a = in[i];
        ushort4 o;
        o.x = f2bf(a.x); o.y = f2bf(a.y); o.z = f2bf(a.z); o.w = f2bf(a.w);
        out[i] = o;
    }
}

// ---- prep: W = sw + bb (sw is pre-masked: sw*sm == sw exactly) --------------
__global__ __launch_bounds__(256) void prep_w_kernel(const float4* __restrict__ sw,
                                                     const float4* __restrict__ bb,
                                                     ushort4* __restrict__ out, int n4) {
    for (int i = blockIdx.x * blockDim.x + threadIdx.x; i < n4; i += gridDim.x * blockDim.x) {
        float4 a = sw[i], b = bb[i];
        ushort4 o;
        o.x = f2bf(a.x + b.x);
        o.y = f2bf(a.y + b.y);
        o.z = f2bf(a.z + b.z);
        o.w = f2bf(a.w + b.w);
        out[i] = o;
    }
}

// ---- main GEMM: C[M,N] = A[M,K] * B[N,K]^T + bias ---------------------------
// R13 = R12 (minimal barriers, 959 TF) + EXTENDED SWIZZLE perm(row) =
// (row&7) ^ ((row>>3)&3). Old perm=row&7 left lanes {l,l+8,l+16,l+24} on the
// same slot -> same 4 banks, 4 rows -> 4-way conflict (2.5e7/dispatch). The
// extra ((row>>3)&3) XOR decollides them. Both sides consistent (rule #21):
// read slot ^= l7 ^ ((l31>>3)&3); stage-side global source col ^= chunk&3
// (per-instr constant), LDS dest stays linear.
__global__ __launch_bounds__(512, 2) void gemm_8p(const short* __restrict__ A,  // [M][K] bf16
                                                  const short* __restrict__ B,  // [N][K] bf16
                                                  const float* __restrict__ bias,
                                                  float* __restrict__ C, int M) {
    __shared__ __align__(16) short As[2][2][8192];  // [buf][half][128 rows x 64 k]
    __shared__ __align__(16) short Bs[2][2][8192];

    const int tid  = threadIdx.x;
    const int lane = tid & 63;
    const int w    = tid >> 6;         // 0..7
    const int wr   = w >> 2;           // 0..1 (A half)
    const int wc   = w & 3;            // 0..3
    const int bh   = wc >> 1;          // B half
    const int l31  = lane & 31;
    const int l5   = lane >> 5;        // 0..1
    const int l7   = lane & 7;
    const int sxr  = l7 ^ ((l31 >> 3) & 3);   // read-side swizzle key

    // XCD-bijective swizzle (nwg = 512, divisible by 8)
    const int bid = blockIdx.x;
    const int swz = (bid & 7) * 64 + (bid >> 3);
    const int bm  = (swz >> 4) * 256;
    const int bn  = (swz & 15) * 256;

    // stage addressing: 8 rows x 128B per wave-instr; LDS[r][s] = G[r][s^perm(r)]
    // perm(r) = (r&7) ^ ((r>>3)&3); within one instr (r>>3)&3 == chunk&3.
    const int srow = lane >> 3;
    const short* Arow = A + (size_t)bm * KK;
    const short* Brow = B + (size_t)bn * KK;

#define STAGE_A(t, h)                                                                      \
    do {                                                                                   \
        _Pragma("unroll") for (int j = 0; j < 2; ++j) {                                    \
            const int ch = w * 2 + j;                                                      \
            const int rr = (h) * 128 + ch * 8 + srow;                                      \
            const int sc = (l7 ^ srow ^ (ch & 3)) * 8;                                     \
            __builtin_amdgcn_global_load_lds(                                              \
                (const __attribute__((address_space(1))) void*)(Arow + (size_t)rr * KK + (t) * 64 + sc), \
                (__attribute__((address_space(3))) void*)(&As[(t) & 1][h][ch * 512]),      \
                16, 0, 0);                                                                 \
        }                                                                                  \
    } while (0)
#define STAGE_B(t, h)                                                                      \
    do {                                                                                   \
        _Pragma("unroll") for (int j = 0; j < 2; ++j) {                                    \
            const int ch = w * 2 + j;                                                      \
            const int rr = (h) * 128 + ch * 8 + srow;                                      \
            const int sc = (l7 ^ srow ^ (ch & 3)) * 8;                                     \
            __builtin_amdgcn_global_load_lds(                                              \
                (const __attribute__((address_space(1))) void*)(Brow + (size_t)rr * KK + (t) * 64 + sc), \
                (__attribute__((address_space(3))) void*)(&Bs[(t) & 1][h][ch * 512]),      \
                16, 0, 0);                                                                 \
        }                                                                                  \
    } while (0)

// region-end sync: own LDS queue drained (cross-wave ds order guard), barrier
#define REGION_BAR()                                          \
    asm volatile("s_waitcnt lgkmcnt(0)" ::: "memory");        \
    __builtin_amdgcn_s_barrier();                             \
    asm volatile("" ::: "memory")

    f32x16 acc[4][2] = {};              // [fm][fn] of 32x32 frags -> 128 VGPRs
    bf16x8 AF1[2][4], AF2[2][4], BF1[4], BF2[4];

    // fragment readers: row = base + l31 (base multiple of 32);
    // slot = (ks*2 + l5) ^ (row&7) ^ ((row>>3)&3) = (ks*2 + l5) ^ sxr
    auto rdA = [&](bf16x8 (&dst)[2][4], int buf, int fmBase) {
#pragma unroll
        for (int fm = 0; fm < 2; ++fm)
#pragma unroll
            for (int ks = 0; ks < 4; ++ks) {
                const int row  = (fmBase + fm) * 32 + l31;
                const int slot = (ks * 2 + l5) ^ sxr;
                dst[fm][ks] = *(const bf16x8*)&As[buf][wr][row * 64 + slot * 8];
            }
    };
    auto rdB = [&](bf16x8 (&dst)[4], int buf, int rowBase) {
#pragma unroll
        for (int ks = 0; ks < 4; ++ks) {
            const int row  = rowBase + l31;
            const int slot = (ks * 2 + l5) ^ sxr;
            dst[ks] = *(const bf16x8*)&Bs[buf][bh][row * 64 + slot * 8];
        }
    };
    auto mmq = [&](f32x16& a0, f32x16& a1, const bf16x8 (&af)[2][4], const bf16x8 (&bf)[4]) {
        __builtin_amdgcn_s_setprio(1);
#pragma unroll
        for (int ks = 0; ks < 4; ++ks) {
            a0 = __builtin_amdgcn_mfma_f32_32x32x16_bf16(af[0][ks], bf[ks], a0, 0, 0, 0);
            a1 = __builtin_amdgcn_mfma_f32_32x32x16_bf16(af[1][ks], bf[ks], a1, 0, 0, 0);
        }
        __builtin_amdgcn_s_setprio(0);
    };

    const int bRow0 = (wc & 1) * 64;    // B within-half row base for fn0

    // prologue: tile0 (A+B) and tile1 B; wait tile0 (leave B1's 4 in flight)
    STAGE_A(0, 0); STAGE_A(0, 1);
    STAGE_B(0, 0); STAGE_B(0, 1);
    STAGE_B(1, 0); STAGE_B(1, 1);
    asm volatile("s_waitcnt vmcnt(4)" ::: "memory");
    __builtin_amdgcn_s_barrier();
    asm volatile("" ::: "memory");

    const int NITER = KK / 128;   // 32 iterations, 2 K-tiles each
    for (int i = 0; i < NITER; ++i) {
        const int t = 2 * i;
        const bool more = (i < NITER - 1);

        // ======== region R1 = P1+P2 (free-run; last Bs[0] read here) ========
        rdA(AF1, 0, 0);
        rdB(BF1, 0, bRow0);
        STAGE_A(t + 1, 0);
        mmq(acc[0][0], acc[1][0], AF1, BF1);
        rdB(BF2, 0, bRow0 + 32);
        STAGE_A(t + 1, 1);
        mmq(acc[0][1], acc[1][1], AF1, BF2);
        REGION_BAR();   // before P3's Bs[0] overwrite

        // ======== region R2 = P3+P4 (stages Bs[0]; last As[0] read here) ====
        rdA(AF2, 0, 2);
        if (more) STAGE_B(t + 2, 0);
        mmq(acc[2][1], acc[3][1], AF2, BF2);
        if (more) STAGE_B(t + 2, 1);
        mmq(acc[2][0], acc[3][0], AF2, BF1);
        asm volatile("s_waitcnt lgkmcnt(0)" ::: "memory");
        if (more) { asm volatile("s_waitcnt vmcnt(4)" ::: "memory"); }
        else      { asm volatile("s_waitcnt vmcnt(0)" ::: "memory"); }
        __builtin_amdgcn_s_barrier();
        asm volatile("" ::: "memory");

        // ======== region R3 = P5+P6 (stages As[0]; last Bs[1] read here) ====
        rdA(AF1, 1, 0);
        rdB(BF1, 1, bRow0);
        if (more) STAGE_A(t + 2, 0);
        mmq(acc[0][0], acc[1][0], AF1, BF1);
        rdB(BF2, 1, bRow0 + 32);
        if (more) STAGE_A(t + 2, 1);
        mmq(acc[0][1], acc[1][1], AF1, BF2);
        REGION_BAR();   // before P7's Bs[1] overwrite

        // ======== region R4 = P7+P8 (stages Bs[1]; last As[1] read here) ====
        rdA(AF2, 1, 2);
        if (more) STAGE_B(t + 3, 0);
        mmq(acc[2][1], acc[3][1], AF2, BF2);
        if (more) STAGE_B(t + 3, 1);
        mmq(acc[2][0], acc[3][0], AF2, BF1);
        asm volatile("s_waitcnt lgkmcnt(0)" ::: "memory");
        if (more) { asm volatile("s_waitcnt vmcnt(4)" ::: "memory"); }
        else      { asm volatile("s_waitcnt vmcnt(0)" ::: "memory"); }
        __builtin_amdgcn_s_barrier();
        asm volatile("" ::: "memory");
    }

#undef STAGE_A
#undef STAGE_B
#undef REGION_BAR

    // epilogue: 32x32 C/D layout col=lane&31, row=(reg&3)+8*(reg>>2)+4*(lane>>5)
#pragma unroll
    for (int fn = 0; fn < 2; ++fn) {
        const int col = bn + wc * 64 + fn * 32 + l31;
        const float bv = bias[col];
#pragma unroll
        for (int fm = 0; fm < 4; ++fm) {
#pragma unroll
            for (int r = 0; r < 16; ++r) {
                const int row = bm + wr * 128 + fm * 32 + (r & 3) + 8 * (r >> 2) + 4 * l5;
                C[(size_t)row * NN + col] = acc[fm][fn][r] + bv;
            }
        }
    }
}

// ---- fp32 fallback (only if workspace too small / odd shape) ----------------
__global__ __launch_bounds__(256) void fallback_gemm(const float* __restrict__ X,
                                                     const float* __restrict__ SW,
                                                     const float* __restrict__ SM,
                                                     const float* __restrict__ BB,
                                                     const float* __restrict__ bias,
                                                     float* __restrict__ C,
                                                     int M, int N, int K) {
    __shared__ float Xs[32][33];
    __shared__ float Ws[32][33];
    const int tid = threadIdx.x;
    const int tx = tid & 31;
    const int ty = tid >> 5;
    const int bm = blockIdx.x * 32, bn = blockIdx.y * 32;
    float acc[4] = {0.f, 0.f, 0.f, 0.f};
    for (int kt = 0; kt < K; kt += 32) {
#pragma unroll
        for (int r = 0; r < 4; ++r) {
            const int row = ty + r * 8;
            Xs[row][tx] = X[(size_t)(bm + row) * K + kt + tx];
            const size_t wi = (size_t)(bn + row) * K + kt + tx;
            Ws[row][tx] = SW[wi] * SM[wi] + BB[wi];
        }
        __syncthreads();
#pragma unroll 8
        for (int k = 0; k < 32; ++k) {
            const float wv = Ws[tx][k];
#pragma unroll
            for (int r = 0; r < 4; ++r)
                acc[r] += Xs[ty + r * 8][k] * wv;
        }
        __syncthreads();
    }
#pragma unroll
    for (int r = 0; r < 4; ++r)
        C[(size_t)(bm + ty + r * 8) * N + bn + tx] = acc[r] + bias[bn + tx];
}

extern "C" void kernel_launch(void* const* d_in, const int* in_sizes, int n_in,
                              void* d_out, int out_size, void* d_ws, size_t ws_size,
                              hipStream_t stream) {
    const float* x    = (const float*)d_in[0];
    const float* sw   = (const float*)d_in[1];
    const float* sm   = (const float*)d_in[2];
    const float* bb   = (const float*)d_in[3];
    const float* bias = (const float*)d_in[4];
    float* out = (float*)d_out;

    const int K = 4096;
    const int N = 4096;
    const int M = in_sizes[0] / K;   // 8192

    const size_t xb_bytes = (size_t)M * K * sizeof(short);
    const size_t wb_bytes = (size_t)N * K * sizeof(short);

    if (ws_size < xb_bytes + wb_bytes || (M % 256) != 0 || in_sizes[1] != N * K) {
        dim3 grid(M / 32, N / 32);
        fallback_gemm<<<grid, 256, 0, stream>>>(x, sw, sm, bb, bias, out, M, N, K);
        return;
    }

    short* xb = (short*)d_ws;
    short* wb = (short*)((char*)d_ws + xb_bytes);

    prep_x_kernel<<<2048, 256, 0, stream>>>((const float4*)x, (ushort4*)xb, (M * K) / 4);
    prep_w_kernel<<<2048, 256, 0, stream>>>((const float4*)sw, (const float4*)bb,
                                            (ushort4*)wb, (N * K) / 4);

    const int nwg = (M / 256) * (N / 256);   // 512
    gemm_8p<<<nwg, 512, 0, stream>>>(xb, wb, bias, out, M);
}